// Round 1
// baseline (2934.681 us; speedup 1.0000x reference)
//
#include <hip/hip_runtime.h>

#ifndef __has_builtin
#define __has_builtin(x) 0
#endif

__device__ __forceinline__ float fexp2(float x) {
#if __has_builtin(__builtin_amdgcn_exp2f)
    return __builtin_amdgcn_exp2f(x);   // v_exp_f32 (2^x)
#else
    return exp2f(x);
#endif
}
__device__ __forceinline__ float flog2(float x) {
#if __has_builtin(__builtin_amdgcn_logf)
    return __builtin_amdgcn_logf(x);    // v_log_f32 (log2 x)
#else
    return log2f(x);
#endif
}

#define NMAXN 128
#define DD    64
#define MAX_ITERS 500

// -1e5 * log2(e)  (NEG surrogate in log2 domain)
#define NEG2  (-144269.50408889634f)
// -(log2(e) / eps), eps = 1e-3 : logK2 = M * LKSC
#define LKSC  (-1442.6950408889634f)
// -(eps * ln2) : M = lk2 * (-eps*ln2); out = acc * OUTSC
#define OUTSC (-6.931471805599453e-4f)

struct SmemStage {
    float A[NMAXN * 33];   // set1 chunk [128][32] padded
    float B[NMAXN * 33];   // set2 chunk
    float nA[NMAXN];       // row norms set1
    float nB[NMAXN];       // row norms set2
};
struct SmemSink {
    float u[NMAXN];
    float v[NMAXN];
    float la[NMAXN];
    float lb[NMAXN];
    float redm[2 * NMAXN]; // cross-wave max combine
    float reds[2 * NMAXN]; // cross-wave sum combine
};
union SmemU {
    SmemStage st;
    SmemSink  sk;
};

__global__ __launch_bounds__(256, 2)
void wasserstein_kernel(const float* __restrict__ x1, const float* __restrict__ x2,
                        const int* __restrict__ sz1, const int* __restrict__ sz2,
                        float* __restrict__ out)
{
    __shared__ SmemU sm;
    __shared__ int   soff[8];
    __shared__ float swred[4];
    __shared__ int   sflag;

    const int b    = blockIdx.x;
    const int tid  = threadIdx.x;
    const int w    = tid >> 6;        // wave 0..3
    const int lane = tid & 63;
    const int tx8  = lane & 7;        // col-within-wave
    const int ty8  = lane >> 3;       // row-within-wave (0..7)
    const int ty   = ((w >> 1) << 3) | ty8;  // 0..15
    const int tx   = ((w & 1) << 3) | tx8;   // 0..15
    const int R0   = ty << 3;         // first owned row
    const int C0   = tx << 3;         // first owned col
    const int halfR = (w >> 1) & 1;   // row-half (for reduce over rows)
    const int halfC = w & 1;          // col-half (for reduce over cols)

    // ---- exclusive prefix sums of sizes (ragged offsets) ----
    int a1 = 0, a2 = 0;
    for (int k = tid; k < b; k += 256) { a1 += sz1[k]; a2 += sz2[k]; }
#pragma unroll
    for (int d = 1; d < 64; d <<= 1) {
        a1 += __shfl_xor(a1, d);
        a2 += __shfl_xor(a2, d);
    }
    if (lane == 0) { soff[w] = a1; soff[4 + w] = a2; }
    if (tid < NMAXN) { sm.st.nA[tid] = 0.f; sm.st.nB[tid] = 0.f; }
    __syncthreads();
    const int off1 = soff[0] + soff[1] + soff[2] + soff[3];
    const int off2 = soff[4] + soff[5] + soff[6] + soff[7];
    const int n1 = sz1[b];
    const int n2 = sz2[b];

    // ---- stage sets in D-chunks of 32, accumulate dots + norms ----
    float dot[8][8];
#pragma unroll
    for (int r = 0; r < 8; ++r)
#pragma unroll
        for (int c = 0; c < 8; ++c) dot[r][c] = 0.f;

    const int srow  = tid >> 1;  // 0..127
    const int shalf = tid & 1;   // 16-float half of chunk

    for (int ch = 0; ch < 2; ++ch) {
        const float* p1 = x1 + (size_t)(off1 + srow) * DD + ch * 32 + shalf * 16;
        const float* p2 = x2 + (size_t)(off2 + srow) * DD + ch * 32 + shalf * 16;
        const bool ok1 = srow < n1;
        const bool ok2 = srow < n2;
        float va[16], vb[16];
#pragma unroll
        for (int q = 0; q < 4; ++q) {
            float4 t1 = ok1 ? ((const float4*)p1)[q] : make_float4(0.f, 0.f, 0.f, 0.f);
            float4 t2 = ok2 ? ((const float4*)p2)[q] : make_float4(0.f, 0.f, 0.f, 0.f);
            va[4*q+0] = t1.x; va[4*q+1] = t1.y; va[4*q+2] = t1.z; va[4*q+3] = t1.w;
            vb[4*q+0] = t2.x; vb[4*q+1] = t2.y; vb[4*q+2] = t2.z; vb[4*q+3] = t2.w;
        }
        float s1 = 0.f, s2 = 0.f;
        const int cb = shalf * 16;
#pragma unroll
        for (int q = 0; q < 16; ++q) {
            sm.st.A[srow * 33 + cb + q] = va[q];
            sm.st.B[srow * 33 + cb + q] = vb[q];
            s1 += va[q] * va[q];
            s2 += vb[q] * vb[q];
        }
        s1 += __shfl_xor(s1, 1);
        s2 += __shfl_xor(s2, 1);
        if (shalf == 0) { sm.st.nA[srow] += s1; sm.st.nB[srow] += s2; }
        __syncthreads();
#pragma unroll 2
        for (int d = 0; d < 32; ++d) {
            float av[8], bv[8];
#pragma unroll
            for (int r = 0; r < 8; ++r) av[r] = sm.st.A[(R0 + r) * 33 + d];
#pragma unroll
            for (int c = 0; c < 8; ++c) bv[c] = sm.st.B[(C0 + c) * 33 + d];
#pragma unroll
            for (int r = 0; r < 8; ++r)
#pragma unroll
                for (int c = 0; c < 8; ++c)
                    dot[r][c] = fmaf(av[r], bv[c], dot[r][c]);
        }
        __syncthreads();
    }

    float rn1[8], rn2[8];
#pragma unroll
    for (int r = 0; r < 8; ++r) rn1[r] = sm.st.nA[R0 + r];
#pragma unroll
    for (int c = 0; c < 8; ++c) rn2[c] = sm.st.nB[C0 + c];

    // logK2 = -M * log2e/eps, M = ||a||^2 + ||b||^2 - 2ab (clamped >= 0)
    float lk[8][8];
#pragma unroll
    for (int r = 0; r < 8; ++r)
#pragma unroll
        for (int c = 0; c < 8; ++c) {
            float M = rn1[r] + rn2[c] - 2.f * dot[r][c];
            M = fmaxf(M, 0.f);
            lk[r][c] = M * LKSC;
        }
    __syncthreads();  // retire staging view of the union

    // ---- Sinkhorn init (log2 domain) ----
    if (tid < NMAXN) {
        sm.sk.u[tid]  = 0.f;
        sm.sk.v[tid]  = 0.f;
        sm.sk.la[tid] = (tid < n1) ? 0.f : NEG2;
        sm.sk.lb[tid] = (tid < n2) ? (flog2((float)n1) - flog2((float)n2)) : NEG2;
    }
    if (tid == 0) sflag = 1;
    __syncthreads();

    float tt[8][8];
    for (int it = 0; it < MAX_ITERS; ++it) {
        // ========== v update: v_j = lb_j - lse_i(lk_ij + u_i) ==========
        float uu[8];
#pragma unroll
        for (int r = 0; r < 8; ++r) uu[r] = sm.sk.u[R0 + r];
        float mx[8];
#pragma unroll
        for (int c = 0; c < 8; ++c) mx[c] = -3.0e38f;
#pragma unroll
        for (int r = 0; r < 8; ++r)
#pragma unroll
            for (int c = 0; c < 8; ++c) {
                tt[r][c] = lk[r][c] + uu[r];
                mx[c] = fmaxf(mx[c], tt[r][c]);
            }
#pragma unroll
        for (int c = 0; c < 8; ++c) {   // in-wave reduce over ty8 (rows)
            mx[c] = fmaxf(mx[c], __shfl_xor(mx[c], 8));
            mx[c] = fmaxf(mx[c], __shfl_xor(mx[c], 16));
            mx[c] = fmaxf(mx[c], __shfl_xor(mx[c], 32));
        }
        if (ty8 == 0) {
#pragma unroll
            for (int c = 0; c < 8; ++c) sm.sk.redm[halfR * NMAXN + C0 + c] = mx[c];
        }
        __syncthreads();                               // B1
        if (tid == 0) sflag = 0;                       // safe window (B1,B2)
#pragma unroll
        for (int c = 0; c < 8; ++c)
            mx[c] = fmaxf(sm.sk.redm[C0 + c], sm.sk.redm[NMAXN + C0 + c]);
        float smc[8];
#pragma unroll
        for (int c = 0; c < 8; ++c) smc[c] = 0.f;
#pragma unroll
        for (int r = 0; r < 8; ++r)
#pragma unroll
            for (int c = 0; c < 8; ++c)
                smc[c] += fexp2(tt[r][c] - mx[c]);
#pragma unroll
        for (int c = 0; c < 8; ++c) {
            smc[c] += __shfl_xor(smc[c], 8);
            smc[c] += __shfl_xor(smc[c], 16);
            smc[c] += __shfl_xor(smc[c], 32);
        }
        if (ty8 == 0) {
#pragma unroll
            for (int c = 0; c < 8; ++c) sm.sk.reds[halfR * NMAXN + C0 + c] = smc[c];
        }
        __syncthreads();                               // B2
        if (ty == 0) {                                 // one writer per column
#pragma unroll
            for (int c = 0; c < 8; ++c) {
                float s  = sm.sk.reds[C0 + c] + sm.sk.reds[NMAXN + C0 + c];
                float vn = sm.sk.lb[C0 + c] - (mx[c] + flog2(s));
                if (vn != sm.sk.v[C0 + c]) sflag = 1;
                sm.sk.v[C0 + c] = vn;
            }
        }
        __syncthreads();                               // B3

        // ========== u update: u_i = la_i - lse_j(lk_ij + v_j) ==========
        float vv[8];
#pragma unroll
        for (int c = 0; c < 8; ++c) vv[c] = sm.sk.v[C0 + c];
        float mr[8];
#pragma unroll
        for (int r = 0; r < 8; ++r) mr[r] = -3.0e38f;
#pragma unroll
        for (int c = 0; c < 8; ++c)
#pragma unroll
            for (int r = 0; r < 8; ++r) {
                tt[r][c] = lk[r][c] + vv[c];
                mr[r] = fmaxf(mr[r], tt[r][c]);
            }
#pragma unroll
        for (int r = 0; r < 8; ++r) {   // in-wave reduce over tx8 (cols)
            mr[r] = fmaxf(mr[r], __shfl_xor(mr[r], 1));
            mr[r] = fmaxf(mr[r], __shfl_xor(mr[r], 2));
            mr[r] = fmaxf(mr[r], __shfl_xor(mr[r], 4));
        }
        if (tx8 == 0) {
#pragma unroll
            for (int r = 0; r < 8; ++r) sm.sk.redm[halfC * NMAXN + R0 + r] = mr[r];
        }
        __syncthreads();                               // B4
#pragma unroll
        for (int r = 0; r < 8; ++r)
            mr[r] = fmaxf(sm.sk.redm[R0 + r], sm.sk.redm[NMAXN + R0 + r]);
        float smr[8];
#pragma unroll
        for (int r = 0; r < 8; ++r) smr[r] = 0.f;
#pragma unroll
        for (int c = 0; c < 8; ++c)
#pragma unroll
            for (int r = 0; r < 8; ++r)
                smr[r] += fexp2(tt[r][c] - mr[r]);
#pragma unroll
        for (int r = 0; r < 8; ++r) {
            smr[r] += __shfl_xor(smr[r], 1);
            smr[r] += __shfl_xor(smr[r], 2);
            smr[r] += __shfl_xor(smr[r], 4);
        }
        if (tx8 == 0) {
#pragma unroll
            for (int r = 0; r < 8; ++r) sm.sk.reds[halfC * NMAXN + R0 + r] = smr[r];
        }
        __syncthreads();                               // B5
        if (tx == 0) {                                 // one writer per row
#pragma unroll
            for (int r = 0; r < 8; ++r) {
                float s  = sm.sk.reds[R0 + r] + sm.sk.reds[NMAXN + R0 + r];
                float un = sm.sk.la[R0 + r] - (mr[r] + flog2(s));
                if (un != sm.sk.u[R0 + r]) sflag = 1;
                sm.sk.u[R0 + r] = un;
            }
        }
        __syncthreads();                               // B6
        if (sflag == 0) break;   // fp32 fixed point: all further iters identical
    }

    // ---- epilogue: out_b = sum_ij M_ij * P_ij = OUTSC * sum_ij lk_ij * 2^(lk+u+v)
    float uu2[8], vv2[8];
#pragma unroll
    for (int r = 0; r < 8; ++r) uu2[r] = sm.sk.u[R0 + r];
#pragma unroll
    for (int c = 0; c < 8; ++c) vv2[c] = sm.sk.v[C0 + c];
    float acc = 0.f;
#pragma unroll
    for (int r = 0; r < 8; ++r)
#pragma unroll
        for (int c = 0; c < 8; ++c)
            acc += lk[r][c] * fexp2(lk[r][c] + uu2[r] + vv2[c]);
#pragma unroll
    for (int d = 1; d < 64; d <<= 1) acc += __shfl_xor(acc, d);
    if (lane == 0) swred[w] = acc;
    __syncthreads();
    if (tid == 0) out[b] = (swred[0] + swred[1] + swred[2] + swred[3]) * OUTSC;
}

extern "C" void kernel_launch(void* const* d_in, const int* in_sizes, int n_in,
                              void* d_out, int out_size, void* d_ws, size_t ws_size,
                              hipStream_t stream) {
    const float* x1  = (const float*)d_in[0];
    const float* x2  = (const float*)d_in[1];
    const int*   sz1 = (const int*)d_in[2];
    const int*   sz2 = (const int*)d_in[3];
    float* out = (float*)d_out;
    hipLaunchKernelGGL(wasserstein_kernel, dim3(512), dim3(256), 0, stream,
                       x1, x2, sz1, sz2, out);
}